// Round 16
// baseline (1028.417 us; speedup 1.0000x reference)
//
#include <hip/hip_runtime.h>

#define IN_F 4096
#define OUT_F 16384
#define MTOK 8192   // B*S

#define BM 128
#define BN 256
#define BK 64
#define NKT (IN_F / BK)   // 64 K-tiles

typedef __attribute__((ext_vector_type(4)))  int   i32x4;
typedef __attribute__((ext_vector_type(4)))  float f32x4;

__device__ __forceinline__ void gload_lds16(const void* g, void* l) {
    __builtin_amdgcn_global_load_lds(
        (const __attribute__((address_space(1))) void*)g,
        (__attribute__((address_space(3))) void*)l,
        16, 0, 0);
}

// ---------------------------------------------------------------------------
// Kernel 1: per-token absmax -> int8 quantize x, store scale
// ---------------------------------------------------------------------------
__global__ __launch_bounds__(256) void k_quant(const float* __restrict__ x,
                                               char* __restrict__ xq,
                                               float* __restrict__ xs) {
    const int m = blockIdx.x;
    const int t = threadIdx.x;
    const float* xrow = x + (size_t)m * IN_F;

    f32x4 v[4];
    float mx = 0.f;
#pragma unroll
    for (int i = 0; i < 4; ++i) {
        v[i] = *(const f32x4*)&xrow[(i * 256 + t) * 4];
        mx = fmaxf(mx, fmaxf(fmaxf(fabsf(v[i].x), fabsf(v[i].y)),
                             fmaxf(fabsf(v[i].z), fabsf(v[i].w))));
    }
#pragma unroll
    for (int off = 32; off > 0; off >>= 1)
        mx = fmaxf(mx, __shfl_xor(mx, off));

    __shared__ float wmax[4];
    const int wid = t >> 6;
    if ((t & 63) == 0) wmax[wid] = mx;
    __syncthreads();
    const float scale = fmaxf(fmaxf(fmaxf(wmax[0], wmax[1]),
                                    fmaxf(wmax[2], wmax[3])), 1e-5f);
    const float inv = 127.0f / scale;

    int* xqi = (int*)(xq + (size_t)m * IN_F);
#pragma unroll
    for (int i = 0; i < 4; ++i) {
        int q0 = (int)rintf(fminf(fmaxf(v[i].x * inv, -128.f), 127.f));
        int q1 = (int)rintf(fminf(fmaxf(v[i].y * inv, -128.f), 127.f));
        int q2 = (int)rintf(fminf(fmaxf(v[i].z * inv, -128.f), 127.f));
        int q3 = (int)rintf(fminf(fmaxf(v[i].w * inv, -128.f), 127.f));
        xqi[i * 256 + t] = (q0 & 255) | ((q1 & 255) << 8) |
                           ((q2 & 255) << 16) | (q3 << 24);
    }
    if (t == 0) xs[m] = scale;
}

// ---------------------------------------------------------------------------
// Kernel 2: ternary int32 weights -> int8 pack
// ---------------------------------------------------------------------------
__global__ __launch_bounds__(256) void k_wconv(const int* __restrict__ wt,
                                               int* __restrict__ w8) {
    const int total4 = OUT_F * IN_F / 4;
    int idx = blockIdx.x * 256 + threadIdx.x;
    const int stride = gridDim.x * 256;
    for (; idx < total4; idx += stride) {
        i32x4 w = *(const i32x4*)&wt[(size_t)idx * 4];
        w8[idx] = (w.x & 255) | ((w.y & 255) << 8) |
                  ((w.z & 255) << 16) | (w.w << 24);
    }
}

// ---------------------------------------------------------------------------
// Kernel 3: i8 GEMM — REGISTER-PIPELINED: wave tile 64x64 (acc 64 AGPR)
// frees registers for a full next-tile fragment double-buffer, removing
// operand gating (the wall since R7: at acc=128 AGPR, 244/256 regs left no
// room; R14 at acc=256 spilled).
//
// 128x256 block, 8 waves (2M x 4N, wave 64x64), BK=64, LDS 72KB:
// A bufs 3 x 8KB at x*8192; B bufs 3 x 16KB at 24576 + x*16384.
//
// Body(kt):  STAGE S(kt+2) -> buf (kt+2)%3   (3 gloads/thread)
//            RD frags(kt+1) from buf (kt+1)%3 -> NXT regs
//            16 MFMA on CUR regs (operands ALREADY in registers)
//            VM0 (S(kt+2) issued a body ago -> latency covered) ; 1 BAR.
// Hazards (single-BAR proof): reads of buf j (body j-1) are lgkm-retired by
// their consuming MFMA (body j) before that wave reaches BAR(j); the next
// write S(j+3) (body j+1) starts only after BAR(j) -> no WAR race. Write->
// read: wave W's VM0 in body(kt) retires its S(kt+2) before BAR(kt); any
// wave's RD of frags(kt+2) is in body(kt+1), after BAR(kt). Race-free.
//
// Swizzle (R10/R12-proven, 0 conflicts): 64B rows, phys chunk =
// logical ^ ((row>>1)&3). Staging: thread t -> row t>>2, phys chunk t&3,
// source chunk (t&3)^((t>>3)&3) (rows +128 preserve the XOR term).
// Frag read: row = lane&15, phys chunk = (lane>>4) ^ ((lane>>1)&3).
//
// XCD map: xcd = bid&7 owns bn band xcd*8 + (idx>>6); bm = idx&63 sweeps
// fastest -> consecutive blocks on an XCD share the SAME 1MB B panel (L2-
// resident). Bijective (4096 % 8 == 0).
// ---------------------------------------------------------------------------
__global__ __launch_bounds__(512, 2) void k_gemm(
    const char*  __restrict__ Aq,     // [MTOK][IN_F] int8
    const char*  __restrict__ Bq,     // [OUT_F][IN_F] int8
    const float* __restrict__ xs,     // [MTOK]
    const float* __restrict__ wsp,    // [1]
    float*       __restrict__ C) {    // [MTOK][OUT_F]
    __shared__ __align__(16) char lds[73728];   // A: 0..24K, B: 24K..72K

    const int t    = threadIdx.x;
    const int lane = t & 63;
    const int wid  = t >> 6;
    const int wr   = wid >> 2;        // 0..1  (M half, 64 rows each)
    const int wc   = wid & 3;         // 0..3  (N quarter, 64 cols each)

    // XCD band map: grid 4096 = 64(M) x 64(N)
    const int bid = blockIdx.x;
    const int idx = bid >> 3;
    const int bn  = (bid & 7) * 8 + (idx >> 6);
    const int bm  = idx & 63;
    const int mBase = bm * BM;
    const int nBase = bn * BN;

    // --- staging source (proven): thread t -> row r0 = t>>2, phys chunk t&3,
    // logical source chunk (t&3)^((t>>3)&3); B second sweep row +128.
    const int r0 = t >> 2;
    const int c0 = (((t & 3) ^ ((t >> 3) & 3)) << 4);

#define STAGE(kt, bx) do {                                                     \
        const size_t ks = (size_t)(kt) * BK;                                   \
        gload_lds16(Aq + (size_t)(mBase + r0) * IN_F + ks + c0,                \
                    lds + (bx) * 8192 + wid * 1024);                           \
        gload_lds16(Bq + (size_t)(nBase + r0) * IN_F + ks + c0,                \
                    lds + 24576 + (bx) * 16384 + wid * 1024);                  \
        gload_lds16(Bq + (size_t)(nBase + 128 + r0) * IN_F + ks + c0,          \
                    lds + 24576 + (bx) * 16384 + 8192 + wid * 1024);           \
    } while (0)

    // --- fragment read (proven, 0 conflicts): row = lane&15,
    // phys chunk = (lane>>4) ^ ((lane>>1)&3)
    const int fOff = (lane & 15) * 64 + ((((lane >> 4) ^ (lane >> 1)) & 3) << 4);
    const char* ldsA = lds + wr * 4096;            // + xA + mi*1024
    const char* ldsB = lds + 24576 + wc * 4096;    // + xB + ni*1024

#define RDF(av, bv, xA, xB) do {                                               \
        _Pragma("unroll")                                                      \
        for (int mi = 0; mi < 4; ++mi)                                         \
            av[mi] = *(const i32x4*)(ldsA + (xA) + mi * 1024 + fOff);          \
        _Pragma("unroll")                                                      \
        for (int ni = 0; ni < 4; ++ni)                                         \
            bv[ni] = *(const i32x4*)(ldsB + (xB) + ni * 1024 + fOff);          \
    } while (0)

#define MFMA16(av, bv)                                                         \
    __builtin_amdgcn_s_setprio(1);                                             \
    _Pragma("unroll")                                                          \
    for (int mi = 0; mi < 4; ++mi)                                             \
        _Pragma("unroll")                                                      \
        for (int ni = 0; ni < 4; ++ni)                                         \
            acc[mi][ni] = __builtin_amdgcn_mfma_i32_16x16x64_i8(               \
                av[mi], bv[ni], acc[mi][ni], 0, 0, 0);                         \
    __builtin_amdgcn_s_setprio(0);

#define BAR()   __builtin_amdgcn_s_barrier()
#define VM0()   asm volatile("s_waitcnt vmcnt(0)" ::: "memory")

    i32x4 acc[4][4];
#pragma unroll
    for (int i = 0; i < 4; ++i)
#pragma unroll
        for (int j = 0; j < 4; ++j)
            acc[i][j] = (i32x4){0, 0, 0, 0};

    i32x4 a0[4], b0[4], a1[4], b1[4];

    // ---- prologue: tiles 0,1 staged; drain both; frags(0) -> set0
    STAGE(0, 0);
    STAGE(1, 1);
    VM0();
    BAR();
    RDF(a0, b0, 0, 0);

    // x1 = (kt+1)%3 buffer offsets, x2 = (kt+2)%3 buffer index
    int x1A = 8192, x1B = 16384, x2 = 2;

#define BODY(kt, AC, BC, AN, BN_) do {                                         \
        if ((kt) + 2 < NKT) STAGE((kt) + 2, x2);                               \
        if ((kt) + 1 < NKT) RDF(AN, BN_, x1A, x1B);                            \
        MFMA16(AC, BC);                                                        \
        if ((kt) + 2 < NKT) { VM0(); BAR(); }                                  \
        x1A = (x1A == 16384) ? 0 : x1A + 8192;                                 \
        x1B = (x1B == 32768) ? 0 : x1B + 16384;                                \
        x2  = (x2 == 2) ? 0 : x2 + 1;                                          \
    } while (0)

    for (int it = 0; it < NKT / 2; ++it) {
        const int k0 = 2 * it;
        BODY(k0,     a0, b0, a1, b1);
        BODY(k0 + 1, a1, b1, a0, b0);
    }

    // ---- epilogue: D row = (lane>>4)*4 + r, col = lane&15 (verified R1-R15)
    const float wsc = wsp[0] * (1.0f / 127.0f);
#pragma unroll
    for (int mi = 0; mi < 4; ++mi) {
        float rs[4];
#pragma unroll
        for (int r = 0; r < 4; ++r)
            rs[r] = xs[mBase + wr * 64 + mi * 16 + (lane >> 4) * 4 + r] * wsc;
#pragma unroll
        for (int ni = 0; ni < 4; ++ni) {
            const int col = nBase + wc * 64 + ni * 16 + (lane & 15);
#pragma unroll
            for (int r = 0; r < 4; ++r) {
                const int row = mBase + wr * 64 + mi * 16 + (lane >> 4) * 4 + r;
                C[(size_t)row * OUT_F + col] = (float)acc[mi][ni][r] * rs[r];
            }
        }
    }
}

// ---------------------------------------------------------------------------
extern "C" void kernel_launch(void* const* d_in, const int* in_sizes, int n_in,
                              void* d_out, int out_size, void* d_ws, size_t ws_size,
                              hipStream_t stream) {
    const float* x   = (const float*)d_in[0];
    const int*   wt  = (const int*)d_in[1];
    const float* wsp = (const float*)d_in[2];
    float* out = (float*)d_out;

    char*  w8 = (char*)d_ws;
    char*  xq = (char*)d_ws + (size_t)OUT_F * IN_F;
    float* xs = (float*)((char*)d_ws + (size_t)OUT_F * IN_F
                                     + (size_t)MTOK * IN_F);

    k_wconv<<<8192, 256, 0, stream>>>(wt, (int*)w8);
    k_quant<<<MTOK, 256, 0, stream>>>(x, xq, xs);

    const int grid = (MTOK / BM) * (OUT_F / BN);  // 64 * 64 = 4096
    k_gemm<<<grid, 512, 0, stream>>>(xq, w8, xs, wsp, out);
}

// Round 17
// 642.580 us; speedup vs baseline: 1.6004x; 1.6004x over previous
//
#include <hip/hip_runtime.h>

#define IN_F 4096
#define OUT_F 16384
#define MTOK 8192   // B*S

#define BM 256
#define BN 256
#define BK 64
#define NKT (IN_F / BK)   // 64 K-tiles

typedef __attribute__((ext_vector_type(4)))  int   i32x4;
typedef __attribute__((ext_vector_type(4)))  float f32x4;

__device__ __forceinline__ void gload_lds16(const void* g, void* l) {
    __builtin_amdgcn_global_load_lds(
        (const __attribute__((address_space(1))) void*)g,
        (__attribute__((address_space(3))) void*)l,
        16, 0, 0);
}

// ---------------------------------------------------------------------------
// Kernel 1: per-token absmax -> int8 quantize x, store scale
// ---------------------------------------------------------------------------
__global__ __launch_bounds__(256) void k_quant(const float* __restrict__ x,
                                               char* __restrict__ xq,
                                               float* __restrict__ xs) {
    const int m = blockIdx.x;
    const int t = threadIdx.x;
    const float* xrow = x + (size_t)m * IN_F;

    f32x4 v[4];
    float mx = 0.f;
#pragma unroll
    for (int i = 0; i < 4; ++i) {
        v[i] = *(const f32x4*)&xrow[(i * 256 + t) * 4];
        mx = fmaxf(mx, fmaxf(fmaxf(fabsf(v[i].x), fabsf(v[i].y)),
                             fmaxf(fabsf(v[i].z), fabsf(v[i].w))));
    }
#pragma unroll
    for (int off = 32; off > 0; off >>= 1)
        mx = fmaxf(mx, __shfl_xor(mx, off));

    __shared__ float wmax[4];
    const int wid = t >> 6;
    if ((t & 63) == 0) wmax[wid] = mx;
    __syncthreads();
    const float scale = fmaxf(fmaxf(fmaxf(wmax[0], wmax[1]),
                                    fmaxf(wmax[2], wmax[3])), 1e-5f);
    const float inv = 127.0f / scale;

    int* xqi = (int*)(xq + (size_t)m * IN_F);
#pragma unroll
    for (int i = 0; i < 4; ++i) {
        int q0 = (int)rintf(fminf(fmaxf(v[i].x * inv, -128.f), 127.f));
        int q1 = (int)rintf(fminf(fmaxf(v[i].y * inv, -128.f), 127.f));
        int q2 = (int)rintf(fminf(fmaxf(v[i].z * inv, -128.f), 127.f));
        int q3 = (int)rintf(fminf(fmaxf(v[i].w * inv, -128.f), 127.f));
        xqi[i * 256 + t] = (q0 & 255) | ((q1 & 255) << 8) |
                           ((q2 & 255) << 16) | (q3 << 24);
    }
    if (t == 0) xs[m] = scale;
}

// ---------------------------------------------------------------------------
// Kernel 2: ternary int32 weights -> int8 pack
// ---------------------------------------------------------------------------
__global__ __launch_bounds__(256) void k_wconv(const int* __restrict__ wt,
                                               int* __restrict__ w8) {
    const int total4 = OUT_F * IN_F / 4;
    int idx = blockIdx.x * 256 + threadIdx.x;
    const int stride = gridDim.x * 256;
    for (; idx < total4; idx += stride) {
        i32x4 w = *(const i32x4*)&wt[(size_t)idx * 4];
        w8[idx] = (w.x & 255) | ((w.y & 255) << 8) |
                  ((w.z & 255) << 16) | (w.w << 24);
    }
}

// ---------------------------------------------------------------------------
// Kernel 3: i8 GEMM — R12 (best measured: 486us, 50.4% MfmaUtil, 0 bank
// conflicts) with ONE change: STAGE(kt+2) moved from sub3 to the TOP of
// sub1, so the staging loads get a full body (~2300 cyc) of in-flight time
// before the VM4 that retires them (R12 issued them only ~330 cyc before
// the next body's VM4 -> residual latency stall, same mechanism that sank
// R16's VM0-per-body).
//
// Hazard proof for the move: stage(kt+2) targets buf (kt+2)%3 = (kt-1)%3,
// whose reads all happened in body(kt-1) and were lgkm-retired before
// BAR(kt-1) (each read's consuming MFMA is in-body); sub1 of body(kt) is
// after BAR(kt-1). Write->read unchanged: VM4 at body(kt) end retires
// s(kt+1) before BAR(kt); reads of tile kt+1 are in body(kt+1).
//
// Everything else identical to R12: 256x256 tile, BK=64, 8 waves 2Mx4N
// (wave 128x64), 3-buffer rotation (A at x*16384, B at 49152+x*16384),
// 64B-row swizzle phys = logical ^ ((row>>1)&3) (0 conflicts), spread-phase
// reads, 2 sub-barriers + VM4 per K-tile, tail VM0.
// ---------------------------------------------------------------------------
__global__ __launch_bounds__(512, 2) void k_gemm(
    const char*  __restrict__ Aq,     // [MTOK][IN_F] int8
    const char*  __restrict__ Bq,     // [OUT_F][IN_F] int8
    const float* __restrict__ xs,     // [MTOK]
    const float* __restrict__ wsp,    // [1]
    float*       __restrict__ C) {    // [MTOK][OUT_F]
    __shared__ __align__(16) char lds[98304];   // A: 0..48K, B: 48K..96K

    const int t    = threadIdx.x;
    const int lane = t & 63;
    const int wid  = t >> 6;
    const int wr   = wid >> 2;        // 0..1  (M half, 128 rows)
    const int wc   = wid & 3;         // 0..3  (N quarter, 64 cols)

    // XCD band mapping: grid 2048 = 32(M) x 64(N); XCD (bid&7) owns an
    // 8-wide bn band. Bijective.
    const int bid = blockIdx.x;
    const int bn  = (bid & 7) * 8 + ((bid >> 3) & 7);
    const int bm  = bid >> 6;
    const int mBase = bm * BM;
    const int nBase = bn * BN;

    // --- staging source (proven): thread t -> row r0 = t>>2, phys chunk t&3,
    // logical source chunk (t&3)^((t>>3)&3); rows +128 preserve the XOR term.
    const int r0 = t >> 2;
    const int c0 = (((t & 3) ^ ((t >> 3) & 3)) << 4);

#define STAGE(kt, bx) do {                                                     \
        const size_t ks = (size_t)(kt) * BK;                                   \
        gload_lds16(Aq + (size_t)(mBase + r0) * IN_F + ks + c0,                \
                    lds + (bx) * 16384 + wid * 1024);                          \
        gload_lds16(Aq + (size_t)(mBase + 128 + r0) * IN_F + ks + c0,          \
                    lds + (bx) * 16384 + 8192 + wid * 1024);                   \
        gload_lds16(Bq + (size_t)(nBase + r0) * IN_F + ks + c0,                \
                    lds + 49152 + (bx) * 16384 + wid * 1024);                  \
        gload_lds16(Bq + (size_t)(nBase + 128 + r0) * IN_F + ks + c0,          \
                    lds + 49152 + (bx) * 16384 + 8192 + wid * 1024);           \
    } while (0)

    // --- fragment read (proven, 0 conflicts): row = lane&15,
    // phys chunk = (lane>>4) ^ ((lane>>1)&3)
    const int fOff = (lane & 15) * 64 + ((((lane >> 4) ^ (lane >> 1)) & 3) << 4);
    const char* ldsA = lds + wr * 8192;            // + x*16384 + mi*1024
    const char* ldsB = lds + 49152 + wc * 4096;    // + x*16384 + ni*1024

#define MFMA8(Af, AB, Bf, NIB)                                                 \
    __builtin_amdgcn_s_setprio(1);                                             \
    _Pragma("unroll")                                                          \
    for (int mi = 0; mi < 4; ++mi)                                             \
        _Pragma("unroll")                                                      \
        for (int ni = 0; ni < 2; ++ni)                                         \
            acc[(AB) + mi][(NIB) + ni] =                                       \
                __builtin_amdgcn_mfma_i32_16x16x64_i8(                         \
                    Af[mi], Bf[ni], acc[(AB) + mi][(NIB) + ni], 0, 0, 0);      \
    __builtin_amdgcn_s_setprio(0);

#define BAR()   __builtin_amdgcn_s_barrier()
#define VM4()   asm volatile("s_waitcnt vmcnt(4)" ::: "memory")
#define VM0()   asm volatile("s_waitcnt vmcnt(0)" ::: "memory")

    i32x4 acc[8][4];
#pragma unroll
    for (int i = 0; i < 8; ++i)
#pragma unroll
        for (int j = 0; j < 4; ++j)
            acc[i][j] = (i32x4){0, 0, 0, 0};

    // ---- prologue: tile0 -> buf0, tile1 -> buf1; VM4 retires tile0 exactly
    STAGE(0, 0);
    STAGE(1, 1);
    VM4();
    BAR();

    int x = 0, x2 = 2;   // kt % 3, (kt+2) % 3
    for (int kt = 0; kt < NKT; ++kt) {
        const int xo = x * 16384;
        const bool more = (kt + 2 < NKT);
        i32x4 aLo[4], aHi[4], bLo[2], bHi[2];

        // ---- sub1: STAGE FIRST (full-body latency coverage), then frags
        // for (lo,lo); MFMA cluster
        if (more) STAGE(kt + 2, x2);
#pragma unroll
        for (int mi = 0; mi < 4; ++mi)
            aLo[mi] = *(const i32x4*)(ldsA + xo + mi * 1024 + fOff);
#pragma unroll
        for (int ni = 0; ni < 2; ++ni)
            bLo[ni] = *(const i32x4*)(ldsB + xo + ni * 1024 + fOff);
        MFMA8(aLo, 0, bLo, 0);

        // ---- sub2: bHi; MFMA (lo,hi)   (issues while sub1 MFMAs run)
#pragma unroll
        for (int ni = 0; ni < 2; ++ni)
            bHi[ni] = *(const i32x4*)(ldsB + xo + (2 + ni) * 1024 + fOff);
        MFMA8(aLo, 0, bHi, 2);

        // ---- sub3: aHi; MFMA (hi,hi)
#pragma unroll
        for (int mi = 0; mi < 4; ++mi)
            aHi[mi] = *(const i32x4*)(ldsA + xo + (4 + mi) * 1024 + fOff);
        MFMA8(aHi, 4, bHi, 2);

        // ---- sub4: MFMA (hi,lo); counted drain; ONE barrier per K-tile
        MFMA8(aHi, 4, bLo, 0);
        if (more) { VM4(); } else { VM0(); }
        BAR();

        x  = (x  == 2) ? 0 : x  + 1;
        x2 = (x2 == 2) ? 0 : x2 + 1;
    }

    // ---- epilogue: D row = (lane>>4)*4 + r, col = lane&15 (verified R1-R16)
    const float wsc = wsp[0] * (1.0f / 127.0f);
#pragma unroll
    for (int mi = 0; mi < 8; ++mi) {
        float rs[4];
#pragma unroll
        for (int r = 0; r < 4; ++r)
            rs[r] = xs[mBase + wr * 128 + mi * 16 + (lane >> 4) * 4 + r] * wsc;
#pragma unroll
        for (int ni = 0; ni < 4; ++ni) {
            const int col = nBase + wc * 64 + ni * 16 + (lane & 15);
#pragma unroll
            for (int r = 0; r < 4; ++r) {
                const int row = mBase + wr * 128 + mi * 16 + (lane >> 4) * 4 + r;
                C[(size_t)row * OUT_F + col] = (float)acc[mi][ni][r] * rs[r];
            }
        }
    }
}

// ---------------------------------------------------------------------------
extern "C" void kernel_launch(void* const* d_in, const int* in_sizes, int n_in,
                              void* d_out, int out_size, void* d_ws, size_t ws_size,
                              hipStream_t stream) {
    const float* x   = (const float*)d_in[0];
    const int*   wt  = (const int*)d_in[1];
    const float* wsp = (const float*)d_in[2];
    float* out = (float*)d_out;

    char*  w8 = (char*)d_ws;
    char*  xq = (char*)d_ws + (size_t)OUT_F * IN_F;
    float* xs = (float*)((char*)d_ws + (size_t)OUT_F * IN_F
                                     + (size_t)MTOK * IN_F);

    k_wconv<<<8192, 256, 0, stream>>>(wt, (int*)w8);
    k_quant<<<MTOK, 256, 0, stream>>>(x, xq, xs);

    const int grid = (MTOK / BM) * (OUT_F / BN);  // 32 * 64 = 2048
    k_gemm<<<grid, 512, 0, stream>>>(xq, w8, xs, wsp, out);
}

// Round 18
// 570.706 us; speedup vs baseline: 1.8020x; 1.1259x over previous
//
#include <hip/hip_runtime.h>

#define IN_F 4096
#define OUT_F 16384
#define MTOK 8192   // B*S

#define BM 256
#define BN 256
#define BKB 128                 // K-bytes (=elements, i8) per K-tile
#define NKT (IN_F / BKB)        // 32 K-tiles
#define NIT (NKT / 2)           // 16 iterations, 2 K-tiles each

typedef __attribute__((ext_vector_type(4)))  int   i32x4;
typedef __attribute__((ext_vector_type(4)))  float f32x4;

__device__ __forceinline__ void gload_lds16(const void* g, void* l) {
    __builtin_amdgcn_global_load_lds(
        (const __attribute__((address_space(1))) void*)g,
        (__attribute__((address_space(3))) void*)l,
        16, 0, 0);
}

// ---------------------------------------------------------------------------
// Kernel 1: per-token absmax -> int8 quantize x, store scale
// ---------------------------------------------------------------------------
__global__ __launch_bounds__(256) void k_quant(const float* __restrict__ x,
                                               char* __restrict__ xq,
                                               float* __restrict__ xs) {
    const int m = blockIdx.x;
    const int t = threadIdx.x;
    const float* xrow = x + (size_t)m * IN_F;

    f32x4 v[4];
    float mx = 0.f;
#pragma unroll
    for (int i = 0; i < 4; ++i) {
        v[i] = *(const f32x4*)&xrow[(i * 256 + t) * 4];
        mx = fmaxf(mx, fmaxf(fmaxf(fabsf(v[i].x), fabsf(v[i].y)),
                             fmaxf(fabsf(v[i].z), fabsf(v[i].w))));
    }
#pragma unroll
    for (int off = 32; off > 0; off >>= 1)
        mx = fmaxf(mx, __shfl_xor(mx, off));

    __shared__ float wmax[4];
    const int wid = t >> 6;
    if ((t & 63) == 0) wmax[wid] = mx;
    __syncthreads();
    const float scale = fmaxf(fmaxf(fmaxf(wmax[0], wmax[1]),
                                    fmaxf(wmax[2], wmax[3])), 1e-5f);
    const float inv = 127.0f / scale;

    int* xqi = (int*)(xq + (size_t)m * IN_F);
#pragma unroll
    for (int i = 0; i < 4; ++i) {
        int q0 = (int)rintf(fminf(fmaxf(v[i].x * inv, -128.f), 127.f));
        int q1 = (int)rintf(fminf(fmaxf(v[i].y * inv, -128.f), 127.f));
        int q2 = (int)rintf(fminf(fmaxf(v[i].z * inv, -128.f), 127.f));
        int q3 = (int)rintf(fminf(fmaxf(v[i].w * inv, -128.f), 127.f));
        xqi[i * 256 + t] = (q0 & 255) | ((q1 & 255) << 8) |
                           ((q2 & 255) << 16) | (q3 << 24);
    }
    if (t == 0) xs[m] = scale;
}

// ---------------------------------------------------------------------------
// Kernel 2: ternary int32 weights -> int8 pack
// ---------------------------------------------------------------------------
__global__ __launch_bounds__(256) void k_wconv(const int* __restrict__ wt,
                                               int* __restrict__ w8) {
    const int total4 = OUT_F * IN_F / 4;
    int idx = blockIdx.x * 256 + threadIdx.x;
    const int stride = gridDim.x * 256;
    for (; idx < total4; idx += stride) {
        i32x4 w = *(const i32x4*)&wt[(size_t)idx * 4];
        w8[idx] = (w.x & 255) | ((w.y & 255) << 8) |
                  ((w.z & 255) << 16) | (w.w << 24);
    }
}

// ---------------------------------------------------------------------------
// Kernel 3: i8 GEMM — BEST MEASURED (round-12 bench: 486us gemm, 50.4%
// MfmaUtil, 0 bank conflicts, total 570.9us). 8-phase schedule with the
// non-load-bearing barriers removed (6 BAR/iter = 3 per K-tile).
//
// Hazard audit: barriers only where (a) the last READ of a region precedes
// a STAGE into it [ph2/ph3/ph6/ph7 ends], and (b) a freshly staged tile is
// about to be read [VM6+BAR at ph4/ph8]. Per-wave read->MFMA ordering is
// compiler-enforced via counted lgkmcnt (plain C++ ds_reads, rule #18 safe).
// Waves slip phase-relative: one wave's ds_reads run under another's MFMAs.
//
// Geometry/swizzle/ledger (all measured): 256x256 tile, BKB=128, 8 waves
// (2Mx4N, wave 128x64). LDS 128KB: A[2buf][2half][128rows][128B], B +64KB.
// phys chunk = logical ^ (row&7); staging permutes global SOURCE within
// each row's 128B. Frag read: row=lane&15, chunk=(kk*4+(lane>>4))^(lane&7).
// VM6@ph4 retires exactly tile 2t+1 (read ph5-8); VM6@ph8 exactly 2t+2.
// Last iter: VM0. Structural ceiling note: measured 4556 cyc/CU/K-tile =
// MFMA 2611 + LDS 2048 serialized; register prefetch (acc=128 AGPR + 116
// VGPR = 244/256) and 2-blocks/CU (needs <=128 regs) are both infeasible,
// per R13-R17 falsifications.
// ---------------------------------------------------------------------------
__global__ __launch_bounds__(512, 2) void k_gemm(
    const char*  __restrict__ Aq,     // [MTOK][IN_F] int8
    const char*  __restrict__ Bq,     // [OUT_F][IN_F] int8
    const float* __restrict__ xs,     // [MTOK]
    const float* __restrict__ wsp,    // [1]
    float*       __restrict__ C) {    // [MTOK][OUT_F]
    __shared__ __align__(16) char lds[131072];   // A: 0..64K, B: 64K..128K

    const int t    = threadIdx.x;
    const int lane = t & 63;
    const int wid  = t >> 6;
    const int wr   = wid >> 2;        // 0..1  (M half)
    const int wc   = wid & 3;         // 0..3  (N quarter)

    // XCD band mapping: grid 2048 = 32(M) x 64(N); XCD (bid&7) owns an
    // 8-wide bn band. Bijective.
    const int bid = blockIdx.x;
    const int bn  = (bid & 7) * 8 + ((bid >> 3) & 7);
    const int bm  = bid >> 6;
    const int mBase = bm * BM;
    const int nBase = bn * BN;

    // --- staging source: phys chunk pc = j*512+t; row = pc>>3,
    // src col-chunk = ((pc&7) ^ (row&7)) * 16
    const int r0 = t >> 3;
    const int c0 = ((t ^ r0) & 7) * 16;

#define STAGE_A(h, b, kt) do {                                                 \
        const size_t _s = (size_t)(mBase + (h) * 128 + r0) * IN_F + c0         \
                        + (size_t)(kt) * BKB;                                  \
        char* _d = lds + (b) * 32768 + (h) * 16384 + wid * 1024;               \
        gload_lds16(Aq + _s, _d);                                              \
        gload_lds16(Aq + _s + (size_t)64 * IN_F, _d + 8192);                   \
    } while (0)
#define STAGE_B(h, b, kt) do {                                                 \
        const size_t _s = (size_t)(nBase + (h) * 128 + r0) * IN_F + c0         \
                        + (size_t)(kt) * BKB;                                  \
        char* _d = lds + 65536 + (b) * 32768 + (h) * 16384 + wid * 1024;       \
        gload_lds16(Bq + _s, _d);                                              \
        gload_lds16(Bq + _s + (size_t)64 * IN_F, _d + 8192);                   \
    } while (0)

    // --- fragment read offsets: row = lane&15, chunk = (kk*4+(lane>>4))^(lane&7)
    int fOff[2];
#pragma unroll
    for (int kk = 0; kk < 2; ++kk)
        fOff[kk] = (lane & 15) * 128 + (((kk * 4 + (lane >> 4)) ^ (lane & 7)) << 4);
    const char* ldsA = lds + wr * 16384;                    // + buf*32768 + mi*2048
    const char* ldsB = lds + 65536 + (wc >> 1) * 16384;     // + buf*32768 + ni*2048
    const int bNi = (wc & 1) * 4;   // wave's ni sub-offset within its B half

#define RD_A(dst, bOfs, miB)                                                   \
    _Pragma("unroll")                                                          \
    for (int mi = 0; mi < 4; ++mi)                                             \
        _Pragma("unroll")                                                      \
        for (int kk = 0; kk < 2; ++kk)                                         \
            dst[mi][kk] = *(const i32x4*)(ldsA + (bOfs) +                      \
                              ((miB) + mi) * 2048 + fOff[kk]);
#define RD_B(dst, bOfs, niB)                                                   \
    _Pragma("unroll")                                                          \
    for (int ni = 0; ni < 2; ++ni)                                             \
        _Pragma("unroll")                                                      \
        for (int kk = 0; kk < 2; ++kk)                                         \
            dst[ni][kk] = *(const i32x4*)(ldsB + (bOfs) +                      \
                              (bNi + (niB) + ni) * 2048 + fOff[kk]);
#define MFMA_Q(Af, MIB, Bf, NIB)                                               \
    __builtin_amdgcn_s_setprio(1);                                             \
    _Pragma("unroll")                                                          \
    for (int mi = 0; mi < 4; ++mi)                                             \
        _Pragma("unroll")                                                      \
        for (int ni = 0; ni < 2; ++ni)                                         \
            _Pragma("unroll")                                                  \
            for (int kk = 0; kk < 2; ++kk)                                     \
                acc[(MIB) + mi][(NIB) + ni] =                                  \
                    __builtin_amdgcn_mfma_i32_16x16x64_i8(                     \
                        Af[mi][kk], Bf[ni][kk], acc[(MIB) + mi][(NIB) + ni],   \
                        0, 0, 0);                                              \
    __builtin_amdgcn_s_setprio(0);
#define BAR()   __builtin_amdgcn_s_barrier()
#define VM6()   asm volatile("s_waitcnt vmcnt(6)" ::: "memory")
#define VM0()   asm volatile("s_waitcnt vmcnt(0)" ::: "memory")

    i32x4 acc[8][4];
#pragma unroll
    for (int i = 0; i < 8; ++i)
#pragma unroll
        for (int j = 0; j < 4; ++j)
            acc[i][j] = (i32x4){0, 0, 0, 0};

    i32x4 aLo[4][2], aHi[4][2], bLo[2][2], bHi[2][2];

    // ---- prologue: tile0 fully (8 loads) + tile1 {B0,B1,A0} (6 loads)
    STAGE_A(0, 0, 0); STAGE_A(1, 0, 0); STAGE_B(0, 0, 0); STAGE_B(1, 0, 0);
    STAGE_B(0, 1, 1); STAGE_B(1, 1, 1); STAGE_A(0, 1, 1);
    VM6();           // tile0's 8 retired; tile1's 6 in flight
    BAR();

    for (int it = 0; it < NIT; ++it) {
        const int kt1 = 2 * it + 1;
        const int kn0 = 2 * it + 2;
        const int kn1 = 2 * it + 3;
        const bool more = (it < NIT - 1);

        // ---- ph1 (no barrier: reads+MFMA flow; slip allowed)
        RD_A(aLo, 0, 0); RD_B(bLo, 0, 0);
        STAGE_A(1, 1, kt1);
        MFMA_Q(aLo, 0, bLo, 0);
        // ---- ph2 (BAR: all B reads of buf0 done -> ph3 may stage B0)
        RD_B(bHi, 0, 2);
        MFMA_Q(aLo, 0, bHi, 2);
        BAR();
        // ---- ph3 (BAR: all A reads of buf0 done -> ph4 may stage A0/B1)
        RD_A(aHi, 0, 4);
        if (more) STAGE_B(0, 0, kn0);
        MFMA_Q(aHi, 4, bHi, 2);
        BAR();
        // ---- ph4 (VM6+BAR: tile 2t+1 fully landed -> ph5 may read buf1)
        if (more) { STAGE_B(1, 0, kn0); STAGE_A(0, 0, kn0); }
        MFMA_Q(aHi, 4, bLo, 0);
        if (more) { VM6(); } else { VM0(); }
        BAR();
        // ---- ph5 (no barrier)
        RD_A(aLo, 32768, 0); RD_B(bLo, 32768, 0);
        if (more) STAGE_A(1, 0, kn0);
        MFMA_Q(aLo, 0, bLo, 0);
        // ---- ph6 (BAR: B reads of buf1 done -> ph7 may stage B1(kn1))
        RD_B(bHi, 32768, 2);
        MFMA_Q(aLo, 0, bHi, 2);
        BAR();
        // ---- ph7 (BAR: A reads of buf1 done -> ph8 A0 / next ph1 A1 stage)
        RD_A(aHi, 32768, 4);
        if (more) STAGE_B(1, 1, kn1);
        MFMA_Q(aHi, 4, bHi, 2);
        BAR();
        // ---- ph8 (VM6+BAR: tile 2t+2 fully landed -> next ph1 reads buf0)
        if (more) { STAGE_B(0, 1, kn1); STAGE_A(0, 1, kn1); }
        MFMA_Q(aHi, 4, bLo, 0);
        if (more) { VM6(); } else { VM0(); }
        BAR();
    }

    // ---- epilogue: D row = (lane>>4)*4 + r, col = lane&15 (verified R1-R17)
    const float wsc = wsp[0] * (1.0f / 127.0f);
#pragma unroll
    for (int mi = 0; mi < 8; ++mi) {
        float rs[4];
#pragma unroll
        for (int r = 0; r < 4; ++r)
            rs[r] = xs[mBase + wr * 128 + mi * 16 + (lane >> 4) * 4 + r] * wsc;
#pragma unroll
        for (int ni = 0; ni < 4; ++ni) {
            const int col = nBase + wc * 64 + ni * 16 + (lane & 15);
#pragma unroll
            for (int r = 0; r < 4; ++r) {
                const int row = mBase + wr * 128 + mi * 16 + (lane >> 4) * 4 + r;
                C[(size_t)row * OUT_F + col] = (float)acc[mi][ni][r] * rs[r];
            }
        }
    }
}

// ---------------------------------------------------------------------------
extern "C" void kernel_launch(void* const* d_in, const int* in_sizes, int n_in,
                              void* d_out, int out_size, void* d_ws, size_t ws_size,
                              hipStream_t stream) {
    const float* x   = (const float*)d_in[0];
    const int*   wt  = (const int*)d_in[1];
    const float* wsp = (const float*)d_in[2];
    float* out = (float*)d_out;

    char*  w8 = (char*)d_ws;
    char*  xq = (char*)d_ws + (size_t)OUT_F * IN_F;
    float* xs = (float*)((char*)d_ws + (size_t)OUT_F * IN_F
                                     + (size_t)MTOK * IN_F);

    k_wconv<<<8192, 256, 0, stream>>>(wt, (int*)w8);
    k_quant<<<MTOK, 256, 0, stream>>>(x, xq, xs);

    const int grid = (MTOK / BM) * (OUT_F / BN);  // 32 * 64 = 2048
    k_gemm<<<grid, 512, 0, stream>>>(xq, w8, xs, wsp, out);
}